// Round 15
// baseline (788.966 us; speedup 1.0000x reference)
//
#include <hip/hip_runtime.h>
#include <hip/hip_bf16.h>
#include <math.h>

typedef __bf16 bf16_t;
typedef __bf16 bf16x8 __attribute__((ext_vector_type(8)));
typedef float f32x4 __attribute__((ext_vector_type(4)));

// async 16B global->LDS (LDS dest must be wave-uniform base + lane*16)
__device__ __forceinline__ void gload16(const bf16_t* g, bf16_t* l) {
  __builtin_amdgcn_global_load_lds(
      (const __attribute__((address_space(1))) unsigned int*)g,
      (__attribute__((address_space(3))) unsigned int*)l, 16, 0, 0);
}

// LDS tiles are [rows][64] bf16 (128 B row stride), contents XOR-swizzled:
// LDS[row][chunk j] holds G[row][chunk j ^ (row&7)]  (chunk = 8 bf16 = 16 B).

// ---------------------------------------------------------------------------
// Layer GEMM (narrow): 128(M)x64(N), BK=64, 128 thr = 2 waves.  proj/FFN2.
// EPI 6: f32 partial d[z][idx] = acc (+bias at z=0)  (split-K, no atomics)
// ---------------------------------------------------------------------------
template<int EPI>
__global__ __launch_bounds__(128, 3) void gemm_bt(
    const bf16_t* __restrict__ A, const bf16_t* __restrict__ W,
    const float* __restrict__ bias,
    bf16_t* __restrict__ obf, float* __restrict__ of32, bf16_t* __restrict__ vt,
    int M, int N, int K, int kLen)
{
  __shared__ bf16_t As[128 * 64];
  __shared__ bf16_t Bs[64 * 64];
  const int tid  = threadIdx.x;
  const int lane = tid & 63;
  const int w    = tid >> 6;          // 0..1, wave's 64-row band
  const long m0 = (long)blockIdx.y * 128;
  const long n0 = (long)blockIdx.x * 64;
  const int k0 = blockIdx.z * kLen;
  const int k1 = k0 + kLen;

  f32x4 acc[4][4] = {};

  const int l7  = lane & 7;
  const int l15 = lane & 15;
  const int hi  = lane >> 4;          // 0..3
  const int rA  = w * 64 + l15;

  for (int kt = k0; kt < k1; kt += 64) {
#pragma unroll
    for (int i = 0; i < 8; ++i) {
      const int cl  = tid + i * 128;
      const int row = cl >> 3;
      const int j   = (cl & 7) ^ (row & 7);
      gload16(A + (m0 + row) * K + kt + (j << 3), As + cl * 8);
    }
#pragma unroll
    for (int i = 0; i < 4; ++i) {
      const int cl  = tid + i * 128;
      const int row = cl >> 3;
      const int j   = (cl & 7) ^ (row & 7);
      gload16(W + (n0 + row) * K + kt + (j << 3), Bs + cl * 8);
    }
    __syncthreads();
#pragma unroll
    for (int kk = 0; kk < 64; kk += 32) {
      const int ck = ((((kk >> 3) + hi) ^ l7) << 3);   // swizzled chunk offset
      bf16x8 af[4], bfr[4];
#pragma unroll
      for (int m = 0; m < 4; ++m) af[m]  = *(const bf16x8*)(As + (rA + m * 16) * 64 + ck);
#pragma unroll
      for (int n = 0; n < 4; ++n) bfr[n] = *(const bf16x8*)(Bs + (l15 + n * 16) * 64 + ck);
#pragma unroll
      for (int m = 0; m < 4; ++m)
#pragma unroll
        for (int n = 0; n < 4; ++n)
          acc[m][n] = __builtin_amdgcn_mfma_f32_16x16x32_bf16(af[m], bfr[n], acc[m][n], 0, 0, 0);
    }
    __syncthreads();
  }

  // C/D layout: col = lane&15, row = (lane>>4)*4 + reg
  const int lr = hi << 2;
#pragma unroll
  for (int n = 0; n < 4; ++n) {
    const long gcol = n0 + n * 16 + l15;
    float bv = 0.f;
    if (EPI == 6 && k0 == 0)  bv = bias[gcol];
#pragma unroll
    for (int m = 0; m < 4; ++m) {
      const long grow0 = m0 + w * 64 + m * 16 + lr;
#pragma unroll
      for (int r = 0; r < 4; ++r) {
        const float v = acc[m][n][r] + bv;
        const long idx = (grow0 + r) * N + gcol;
        of32[(long)blockIdx.z * ((long)M * N) + idx] = v;
      }
    }
  }
}

// ---------------------------------------------------------------------------
// Layer GEMM (wide, logits-proven config): 128(M)x128(N), BK=64, 256 thr =
// 4 waves (2M x 2N), (256,3).  QKV (EPI5) and FFN1 (EPI1).
// EPI 5: bf16 out = acc + bias, + side-write V third into vT[bh][d][s]
// EPI 1: bf16 out = gelu(acc + bias)
// ---------------------------------------------------------------------------
template<int EPI>
__global__ __launch_bounds__(256, 3) void gemm_bt2(
    const bf16_t* __restrict__ A, const bf16_t* __restrict__ W,
    const float* __restrict__ bias,
    bf16_t* __restrict__ obf, bf16_t* __restrict__ vt,
    int M, int N, int K)
{
  __shared__ bf16_t As[128 * 64];
  __shared__ bf16_t Bs[128 * 64];
  const int tid  = threadIdx.x;
  const int lane = tid & 63;
  const int w    = tid >> 6;
  const int wr   = w >> 1;
  const int wc   = w & 1;
  const long m0 = (long)blockIdx.y * 128;
  const long n0 = (long)blockIdx.x * 128;

  f32x4 acc[4][4] = {};
  const int l7  = lane & 7;
  const int l15 = lane & 15;
  const int hi  = lane >> 4;
  const int rA  = wr * 64 + l15;
  const int rB  = wc * 64 + l15;

  for (int kt = 0; kt < K; kt += 64) {
#pragma unroll
    for (int i = 0; i < 4; ++i) {
      const int cl  = tid + i * 256;
      const int row = cl >> 3;
      const int j   = (cl & 7) ^ (row & 7);
      gload16(A + (m0 + row) * K + kt + (j << 3), As + cl * 8);
    }
#pragma unroll
    for (int i = 0; i < 4; ++i) {
      const int cl  = tid + i * 256;
      const int row = cl >> 3;
      const int j   = (cl & 7) ^ (row & 7);
      gload16(W + (n0 + row) * K + kt + (j << 3), Bs + cl * 8);
    }
    __syncthreads();
#pragma unroll
    for (int kk = 0; kk < 64; kk += 32) {
      const int ck = ((((kk >> 3) + hi) ^ l7) << 3);
      bf16x8 af[4], bfr[4];
#pragma unroll
      for (int m = 0; m < 4; ++m) af[m]  = *(const bf16x8*)(As + (rA + m * 16) * 64 + ck);
#pragma unroll
      for (int n = 0; n < 4; ++n) bfr[n] = *(const bf16x8*)(Bs + (rB + n * 16) * 64 + ck);
#pragma unroll
      for (int m = 0; m < 4; ++m)
#pragma unroll
        for (int n = 0; n < 4; ++n)
          acc[m][n] = __builtin_amdgcn_mfma_f32_16x16x32_bf16(af[m], bfr[n], acc[m][n], 0, 0, 0);
    }
    __syncthreads();
  }

  const int lr = hi << 2;
#pragma unroll
  for (int n = 0; n < 4; ++n) {
    const long gcol = n0 + wc * 64 + n * 16 + l15;
    const float bv = bias[gcol];
    int hq = 0, c = 0;
    if (EPI == 5) { hq = (int)gcol / 192; c = (int)gcol - hq * 192; }
#pragma unroll
    for (int m = 0; m < 4; ++m) {
      const long grow0 = m0 + wr * 64 + m * 16 + lr;
#pragma unroll
      for (int r = 0; r < 4; ++r) {
        float v = acc[m][n][r] + bv;
        const long idx = (grow0 + r) * N + gcol;
        if (EPI == 5) {
          obf[idx] = (bf16_t)v;
          if (c >= 128) {
            const int row = (int)(grow0 + r);
            const int bb = row >> 10, ss = row & 1023;
            vt[(((long)bb * 12 + hq) * 64 + (c - 128)) * 1024 + ss] = (bf16_t)v;
          }
        } else {
          v = 0.5f * v * (1.0f + erff(v * 0.70710678118654752f));
          obf[idx] = (bf16_t)v;
        }
      }
    }
  }
}

// ---------------------------------------------------------------------------
// Logits GEMM: out[2048,32000] f32 = A[2048,768] @ We[32000,768]^T, both bf16.
// 256-thread 128x128 structure, BK=64, swizzled LDS, XCD-chunked M-fastest
// grid, NT fp32 stores, 3 blocks/CU.
// ---------------------------------------------------------------------------
__global__ __launch_bounds__(256, 3) void gemm_logits(
    const bf16_t* __restrict__ A, const bf16_t* __restrict__ W,
    float* __restrict__ out)
{
  __shared__ bf16_t As[128 * 64];
  __shared__ bf16_t Bs[128 * 64];
  const int tid  = threadIdx.x;
  const int lane = tid & 63;
  const int w    = tid >> 6;
  const int wr   = w >> 1;
  const int wc   = w & 1;
  const int d    = blockIdx.x;            // 0..3999
  const int wk   = (d & 7) * 500 + (d >> 3);
  const long m0  = (long)(wk & 15) * 128; // M fastest within XCD chunk
  const long n0  = (long)(wk >> 4) * 128;
  const int K = 768, N = 32000;

  f32x4 acc[4][4] = {};
  const int l7  = lane & 7;
  const int l15 = lane & 15;
  const int hi  = lane >> 4;
  const int rA  = wr * 64 + l15;
  const int rB  = wc * 64 + l15;

  for (int kt = 0; kt < K; kt += 64) {
#pragma unroll
    for (int i = 0; i < 4; ++i) {
      const int cl  = tid + i * 256;
      const int row = cl >> 3;
      const int j   = (cl & 7) ^ (row & 7);
      gload16(A + (m0 + row) * K + kt + (j << 3), As + cl * 8);
    }
#pragma unroll
    for (int i = 0; i < 4; ++i) {
      const int cl  = tid + i * 256;
      const int row = cl >> 3;
      const int j   = (cl & 7) ^ (row & 7);
      gload16(W + (n0 + row) * K + kt + (j << 3), Bs + cl * 8);
    }
    __syncthreads();
#pragma unroll
    for (int kk = 0; kk < 64; kk += 32) {
      const int ck = ((((kk >> 3) + hi) ^ l7) << 3);
      bf16x8 af[4], bfr[4];
#pragma unroll
      for (int m = 0; m < 4; ++m) af[m]  = *(const bf16x8*)(As + (rA + m * 16) * 64 + ck);
#pragma unroll
      for (int n = 0; n < 4; ++n) bfr[n] = *(const bf16x8*)(Bs + (rB + n * 16) * 64 + ck);
#pragma unroll
      for (int m = 0; m < 4; ++m)
#pragma unroll
        for (int n = 0; n < 4; ++n)
          acc[m][n] = __builtin_amdgcn_mfma_f32_16x16x32_bf16(af[m], bfr[n], acc[m][n], 0, 0, 0);
    }
    __syncthreads();
  }

  const int lr = hi << 2;
#pragma unroll
  for (int n = 0; n < 4; ++n) {
    const long gcol = n0 + wc * 64 + n * 16 + l15;
#pragma unroll
    for (int m = 0; m < 4; ++m) {
      const long grow0 = m0 + wr * 64 + m * 16 + lr;
#pragma unroll
      for (int r = 0; r < 4; ++r)
        __builtin_nontemporal_store(acc[m][n][r], &out[(grow0 + r) * N + gcol]);
    }
  }
}

// ---------------------------------------------------------------------------
// Flash attention: one wave per (b, h, 16 q-rows). KV blocks of 64, causal.
// CAUSAL LOAD-BALANCED block mapping: block = (bh, k), its 4 waves take
// qt in {2k, 2k+1, 63-2k, 62-2k} -- per-block work is constant (sum 126).
// Q,K from qkv [B][S][2304]; V from vT [bh][64][1024]. T13 defer-max.
// ---------------------------------------------------------------------------
__global__ __launch_bounds__(256) void attn_kernel(
    const bf16_t* __restrict__ qkv, const bf16_t* __restrict__ vT,
    bf16_t* __restrict__ aout)
{
  __shared__ bf16_t Plds[4][16 * 64];
  const int tid  = threadIdx.x;
  const int lane = tid & 63;
  const int w    = tid >> 6;
  const int bh   = blockIdx.x >> 4;      // 0..23
  const int k    = blockIdx.x & 15;      // 0..15
  const int qt   = (w < 2) ? (2 * k + w) : (63 - 2 * k - (w & 1));
  const int b    = bh / 12;
  const int h    = bh % 12;
  const int q0   = qt << 4;

  const bf16_t* base = qkv + (long)b * 1024 * 2304 + h * 192;
  const bf16_t* vtb  = vT + (long)bh * 64 * 1024;
  const int koff  = (lane >> 4) << 3;
  const int l15   = lane & 15;
  const int rbase = (lane >> 4) << 2;

  const bf16x8 qf0 = *(const bf16x8*)(base + (long)(q0 + l15) * 2304 + koff);
  const bf16x8 qf1 = *(const bf16x8*)(base + (long)(q0 + l15) * 2304 + 32 + koff);

  f32x4 acc[4] = {};
  float mrun[4], lrun[4];
#pragma unroll
  for (int r = 0; r < 4; ++r) { mrun[r] = -1e30f; lrun[r] = 0.f; }

  bf16_t* pl = &Plds[w][0];
  const int kbmax = (q0 + 15) >> 6;
  for (int kb = 0; kb <= kbmax; ++kb) {
    const int kv0 = kb << 6;
    const f32x4 z = {0.f, 0.f, 0.f, 0.f};
    f32x4 s[4];
    __builtin_amdgcn_s_setprio(1);
#pragma unroll
    for (int g = 0; g < 4; ++g) {
      const bf16_t* kr = base + 64 + (long)(kv0 + g * 16 + l15) * 2304;
      const bf16x8 ka = *(const bf16x8*)(kr + koff);
      const bf16x8 kb2 = *(const bf16x8*)(kr + 32 + koff);
      s[g] = __builtin_amdgcn_mfma_f32_16x16x32_bf16(qf0, ka, z, 0, 0, 0);
      s[g] = __builtin_amdgcn_mfma_f32_16x16x32_bf16(qf1, kb2, s[g], 0, 0, 0);
    }
    __builtin_amdgcn_s_setprio(0);

#pragma unroll
    for (int r = 0; r < 4; ++r) {
      const int qi = q0 + rbase + r;
      float v[4];
#pragma unroll
      for (int g = 0; g < 4; ++g)
        v[g] = (kv0 + g * 16 + l15 <= qi) ? s[g][r] * 0.125f : -1e9f;
      float mx = fmaxf(fmaxf(v[0], v[1]), fmaxf(v[2], v[3]));
#pragma unroll
      for (int dd = 1; dd < 16; dd <<= 1) mx = fmaxf(mx, __shfl_xor(mx, dd));
      if (mx > mrun[r] + 8.f) {
        const float sc = __expf(mrun[r] - mx);
        lrun[r] *= sc;
        acc[0][r] *= sc; acc[1][r] *= sc; acc[2][r] *= sc; acc[3][r] *= sc;
        mrun[r] = mx;
      }
      float p[4], sm = 0.f;
#pragma unroll
      for (int g = 0; g < 4; ++g) { p[g] = __expf(v[g] - mrun[r]); sm += p[g]; }
#pragma unroll
      for (int dd = 1; dd < 16; dd <<= 1) sm += __shfl_xor(sm, dd);
      lrun[r] += sm;
#pragma unroll
      for (int g = 0; g < 4; ++g)
        pl[(rbase + r) * 64 + g * 16 + l15] = (bf16_t)p[g];
    }
    asm volatile("s_waitcnt lgkmcnt(0)" ::: "memory");
    const bf16x8 pf0 = *(const bf16x8*)(pl + l15 * 64 + koff);
    const bf16x8 pf1 = *(const bf16x8*)(pl + l15 * 64 + 32 + koff);
    __builtin_amdgcn_s_setprio(1);
#pragma unroll
    for (int hh = 0; hh < 2; ++hh) {
      const bf16x8 pf = hh ? pf1 : pf0;
      const int sbase = kv0 + hh * 32 + koff;
#pragma unroll
      for (int cb = 0; cb < 4; ++cb) {
        const bf16x8 vf = *(const bf16x8*)(vtb + (long)(cb * 16 + l15) * 1024 + sbase);
        acc[cb] = __builtin_amdgcn_mfma_f32_16x16x32_bf16(pf, vf, acc[cb], 0, 0, 0);
      }
    }
    __builtin_amdgcn_s_setprio(0);
  }

#pragma unroll
  for (int cb = 0; cb < 4; ++cb)
#pragma unroll
    for (int r = 0; r < 4; ++r) {
      const float o = acc[cb][r] / lrun[r];
      aout[(long)(b * 1024 + q0 + rbase + r) * 768 + h * 64 + cb * 16 + l15] = (bf16_t)o;
    }
}

// ---------------------------------------------------------------------------
// Residual-folding LayerNorm: x += d[0] + d[1] (split-K partials from EPI6),
// write x back, then out = LN(x).
// ---------------------------------------------------------------------------
__global__ __launch_bounds__(256) void ln_fuse2(
    float* __restrict__ x, const float* __restrict__ dl,
    const float* __restrict__ g, const float* __restrict__ bta,
    bf16_t* __restrict__ out)
{
  const int row = blockIdx.x;
  const int tid = threadIdx.x;
  float* xr = x + (long)row * 768;
  const float* d0 = dl + (long)row * 768;
  const float* d1 = d0 + 1572864;
  float v[3];
#pragma unroll
  for (int k = 0; k < 3; ++k) {
    const int c = tid + k * 256;
    const float t = xr[c] + d0[c] + d1[c];
    v[k] = t;
    xr[c] = t;
  }
  float s  = v[0] + v[1] + v[2];
  float ss = v[0] * v[0] + v[1] * v[1] + v[2] * v[2];
#pragma unroll
  for (int d = 1; d < 64; d <<= 1) { s += __shfl_xor(s, d); ss += __shfl_xor(ss, d); }
  __shared__ float sh[8];
  const int lane = tid & 63, wv = tid >> 6;
  if (lane == 0) { sh[wv] = s; sh[4 + wv] = ss; }
  __syncthreads();
  s  = sh[0] + sh[1] + sh[2] + sh[3];
  ss = sh[4] + sh[5] + sh[6] + sh[7];
  const float mean = s * (1.0f / 768.0f);
  const float var  = ss * (1.0f / 768.0f) - mean * mean;
  const float inv  = rsqrtf(var + 1e-5f);
  bf16_t* orow = out + (long)row * 768;
#pragma unroll
  for (int k = 0; k < 3; ++k) {
    const int c = tid + k * 256;
    orow[c] = (bf16_t)(g[c] * ((v[k] - mean) * inv) + bta[c]);
  }
}

// ---------------------------------------------------------------------------
// Fused embedding + first LayerNorm:
// x = W_emb[id]*sqrt(768) + pos ; h = LN(x, g, b)
// ---------------------------------------------------------------------------
__global__ __launch_bounds__(256) void embed_ln(
    const int* __restrict__ ids, const float* __restrict__ We,
    const float* __restrict__ pos, const float* __restrict__ g,
    const float* __restrict__ bta, float* __restrict__ x,
    bf16_t* __restrict__ out)
{
  const int row = blockIdx.x;
  const int tid = threadIdx.x;
  const int sidx = row & 1023;
  const long id = ids[row];
  const float* wr = We + id * 768;
  const float* pr = pos + (long)sidx * 768;
  float* xr = x + (long)row * 768;
  float v[3];
#pragma unroll
  for (int k = 0; k < 3; ++k) {
    const int c = tid + k * 256;
    const float t = wr[c] * 27.712812921102035f + pr[c];
    v[k] = t;
    xr[c] = t;
  }
  float s  = v[0] + v[1] + v[2];
  float ss = v[0] * v[0] + v[1] * v[1] + v[2] * v[2];
#pragma unroll
  for (int d = 1; d < 64; d <<= 1) { s += __shfl_xor(s, d); ss += __shfl_xor(ss, d); }
  __shared__ float sh[8];
  const int lane = tid & 63, wv = tid >> 6;
  if (lane == 0) { sh[wv] = s; sh[4 + wv] = ss; }
  __syncthreads();
  s  = sh[0] + sh[1] + sh[2] + sh[3];
  ss = sh[4] + sh[5] + sh[6] + sh[7];
  const float mean = s * (1.0f / 768.0f);
  const float var  = ss * (1.0f / 768.0f) - mean * mean;
  const float inv  = rsqrtf(var + 1e-5f);
  bf16_t* orow = out + (long)row * 768;
#pragma unroll
  for (int k = 0; k < 3; ++k) {
    const int c = tid + k * 256;
    orow[c] = (bf16_t)(g[c] * ((v[k] - mean) * inv) + bta[c]);
  }
}

// ---------------------------------------------------------------------------
// Fused fp32 -> bf16 conversion of all 5 weight tensors (contiguous outputs).
// ---------------------------------------------------------------------------
__global__ __launch_bounds__(256) void cvt_all_kernel(
    const float* __restrict__ s0, const float* __restrict__ s1,
    const float* __restrict__ s2, const float* __restrict__ s3,
    const float* __restrict__ s4, bf16_t* __restrict__ out)
{
  const int b = blockIdx.x;
  const float* src; long rel, obase;
  if      (b < 3456)  { src = s0; rel = (long)b * 2048;          obase = 0;        }
  else if (b < 4608)  { src = s1; rel = (long)(b - 3456) * 2048; obase = 7077888;  }
  else if (b < 9216)  { src = s2; rel = (long)(b - 4608) * 2048; obase = 9437184;  }
  else if (b < 13824) { src = s3; rel = (long)(b - 9216) * 2048; obase = 18874368; }
  else                { src = s4; rel = (long)(b - 13824) * 2048; obase = 28311552; }
  const long i = rel + (long)threadIdx.x * 8;
  const f32x4 a = *(const f32x4*)(src + i);
  const f32x4 c = *(const f32x4*)(src + i + 4);
  bf16x8 o;
#pragma unroll
  for (int j = 0; j < 4; ++j) { o[j] = (bf16_t)a[j]; o[4 + j] = (bf16_t)c[j]; }
  *(bf16x8*)(out + obase + i) = o;
}

// ---------------------------------------------------------------------------
extern "C" void kernel_launch(void* const* d_in, const int* in_sizes, int n_in,
                              void* d_out, int out_size, void* d_ws, size_t ws_size,
                              hipStream_t stream)
{
  const float* W_emb = (const float*)d_in[0];
  const float* pos   = (const float*)d_in[1];
  const float* n1g   = (const float*)d_in[2];
  const float* n1b   = (const float*)d_in[3];
  const float* qkvw  = (const float*)d_in[4];
  const float* qkvb  = (const float*)d_in[5];
  const float* projw = (const float*)d_in[6];
  const float* projb = (const float*)d_in[7];
  const float* n2g   = (const float*)d_in[8];
  const float* n2b   = (const float*)d_in[9];
  const float* f1w   = (const float*)d_in[10];
  const float* f1b   = (const float*)d_in[11];
  const float* f2w   = (const float*)d_in[12];
  const float* f2b   = (const float*)d_in[13];
  const float* fing  = (const float*)d_in[14];
  const float* finb  = (const float*)d_in[15];
  const int*   ids   = (const int*)d_in[16];
  float* out = (float*)d_out;

  char* ws = (char*)d_ws;
  float*  x     = (float*)(ws);                 // 2048*768 f32   = 6291456 B
  bf16_t* h     = (bf16_t*)(ws + 6291456);      // 2048*768 bf16  = 3145728 B
  bf16_t* qkv   = (bf16_t*)(ws + 9437184);      // 2048*2304 bf16 = 9437184 B
  bf16_t* attn  = (bf16_t*)(ws + 18874368);     // 2048*768 bf16
  bf16_t* ffn1o = (bf16_t*)(ws + 22020096);     // 2048*3072 bf16 = 12582912 B
  bf16_t* Wq    = (bf16_t*)(ws + 34603008);     // 4*2304*768   } contiguous
  bf16_t* Wp    = (bf16_t*)(ws + 48758784);     // 4*768*768    }
  bf16_t* W1    = (bf16_t*)(ws + 53477376);     // 4*3072*768   }
  bf16_t* W2    = (bf16_t*)(ws + 72351744);     // 4*768*3072   }
  bf16_t* We    = (bf16_t*)(ws + 91226112);     // 32000*768    }
  bf16_t* vT    = (bf16_t*)(ws + 140378112);    // 24*64*1024 bf16 = 3145728 B
  float*  dpart = (float*)(ws + 143523840);     // 2 x 2048*768 f32 = 12582912 B

  cvt_all_kernel<<<dim3(25824), 256, 0, stream>>>(qkvw, projw, f1w, f2w, W_emb, Wq);

  embed_ln<<<2048, 256, 0, stream>>>(ids, W_emb, pos, n1g, n1b, x, h);

  for (int i = 0; i < 4; ++i) {
    if (i > 0)
      ln_fuse2<<<2048, 256, 0, stream>>>(x, dpart, n1g + i * 768, n1b + i * 768, h);
    gemm_bt2<5><<<dim3(18, 16), 256, 0, stream>>>(
        h, Wq + (long)i * 2304 * 768, qkvb + i * 2304, qkv, vT, 2048, 2304, 768);
    attn_kernel<<<384, 256, 0, stream>>>(qkv, vT, attn);
    gemm_bt<6><<<dim3(12, 16, 2), 128, 0, stream>>>(
        attn, Wp + (long)i * 768 * 768, projb + i * 768, nullptr, dpart, nullptr,
        2048, 768, 768, 384);
    ln_fuse2<<<2048, 256, 0, stream>>>(x, dpart, n2g + i * 768, n2b + i * 768, h);
    gemm_bt2<1><<<dim3(24, 16), 256, 0, stream>>>(
        h, W1 + (long)i * 3072 * 768, f1b + i * 3072, ffn1o, nullptr, 2048, 3072, 768);
    gemm_bt<6><<<dim3(12, 16, 2), 128, 0, stream>>>(
        ffn1o, W2 + (long)i * 768 * 3072, f2b + i * 768, nullptr, dpart, nullptr,
        2048, 768, 3072, 1536);
  }
  ln_fuse2<<<2048, 256, 0, stream>>>(x, dpart, fing, finb, h);
  gemm_logits<<<dim3(4000), 256, 0, stream>>>(h, We, out);
}

// Round 16
// 757.434 us; speedup vs baseline: 1.0416x; 1.0416x over previous
//
#include <hip/hip_runtime.h>
#include <hip/hip_bf16.h>
#include <math.h>

typedef __bf16 bf16_t;
typedef __bf16 bf16x8 __attribute__((ext_vector_type(8)));
typedef float f32x4 __attribute__((ext_vector_type(4)));

// async 16B global->LDS (LDS dest must be wave-uniform base + lane*16)
__device__ __forceinline__ void gload16(const bf16_t* g, bf16_t* l) {
  __builtin_amdgcn_global_load_lds(
      (const __attribute__((address_space(1))) unsigned int*)g,
      (__attribute__((address_space(3))) unsigned int*)l, 16, 0, 0);
}

// LDS tiles are [rows][64] bf16 (128 B row stride), contents XOR-swizzled:
// LDS[row][chunk j] holds G[row][chunk j ^ (row&7)]  (chunk = 8 bf16 = 16 B).

// ---------------------------------------------------------------------------
// Layer GEMM: out[M,N] = A[M,K] @ W[N,K]^T (+bias, +epilogue)
// EPI 0: bf16 out = acc + bias            (generic)
// EPI 5: EPI0 + side-write V third into vT[bh][d][s]   (QKV, fused vtrans)
// EPI 1: bf16 out = gelu(acc + bias)      (FFN1)
// EPI 6: f32 partial d[z][idx] = acc (+bias at z=0)    (proj/FFN2 split-K;
//        NO atomics -- reduction folded into the next ln_fuse2 kernel)
// Tile 128(M)x64(N), BK=64, 128 threads = 2 waves, single-buffer LDS.
// ---------------------------------------------------------------------------
template<int EPI>
__global__ __launch_bounds__(128, 3) void gemm_bt(
    const bf16_t* __restrict__ A, const bf16_t* __restrict__ W,
    const float* __restrict__ bias,
    bf16_t* __restrict__ obf, float* __restrict__ of32, bf16_t* __restrict__ vt,
    int M, int N, int K, int kLen)
{
  __shared__ bf16_t As[128 * 64];
  __shared__ bf16_t Bs[64 * 64];
  const int tid  = threadIdx.x;
  const int lane = tid & 63;
  const int w    = tid >> 6;          // 0..1, wave's 64-row band
  const long m0 = (long)blockIdx.y * 128;
  const long n0 = (long)blockIdx.x * 64;
  const int k0 = blockIdx.z * kLen;
  const int k1 = k0 + kLen;

  f32x4 acc[4][4] = {};

  const int l7  = lane & 7;
  const int l15 = lane & 15;
  const int hi  = lane >> 4;          // 0..3
  const int rA  = w * 64 + l15;

  for (int kt = k0; kt < k1; kt += 64) {
#pragma unroll
    for (int i = 0; i < 8; ++i) {
      const int cl  = tid + i * 128;
      const int row = cl >> 3;
      const int j   = (cl & 7) ^ (row & 7);
      gload16(A + (m0 + row) * K + kt + (j << 3), As + cl * 8);
    }
#pragma unroll
    for (int i = 0; i < 4; ++i) {
      const int cl  = tid + i * 128;
      const int row = cl >> 3;
      const int j   = (cl & 7) ^ (row & 7);
      gload16(W + (n0 + row) * K + kt + (j << 3), Bs + cl * 8);
    }
    __syncthreads();
#pragma unroll
    for (int kk = 0; kk < 64; kk += 32) {
      const int ck = ((((kk >> 3) + hi) ^ l7) << 3);   // swizzled chunk offset
      bf16x8 af[4], bfr[4];
#pragma unroll
      for (int m = 0; m < 4; ++m) af[m]  = *(const bf16x8*)(As + (rA + m * 16) * 64 + ck);
#pragma unroll
      for (int n = 0; n < 4; ++n) bfr[n] = *(const bf16x8*)(Bs + (l15 + n * 16) * 64 + ck);
#pragma unroll
      for (int m = 0; m < 4; ++m)
#pragma unroll
        for (int n = 0; n < 4; ++n)
          acc[m][n] = __builtin_amdgcn_mfma_f32_16x16x32_bf16(af[m], bfr[n], acc[m][n], 0, 0, 0);
    }
    __syncthreads();
  }

  // C/D layout: col = lane&15, row = (lane>>4)*4 + reg
  const int lr = hi << 2;
#pragma unroll
  for (int n = 0; n < 4; ++n) {
    const long gcol = n0 + n * 16 + l15;
    float bv = 0.f;
    if (EPI == 0 || EPI == 1 || EPI == 5) bv = bias[gcol];
    if (EPI == 6 && k0 == 0)  bv = bias[gcol];
    const int hq = (int)gcol / 192;          // head (EPI5)
    const int c  = (int)gcol - hq * 192;     // col within head
#pragma unroll
    for (int m = 0; m < 4; ++m) {
      const long grow0 = m0 + w * 64 + m * 16 + lr;
#pragma unroll
      for (int r = 0; r < 4; ++r) {
        float v = acc[m][n][r] + bv;
        const long idx = (grow0 + r) * N + gcol;
        if (EPI == 0 || EPI == 5) {
          obf[idx] = (bf16_t)v;
          if (EPI == 5 && c >= 128) {
            const int row = (int)(grow0 + r);
            const int bb = row >> 10, ss = row & 1023;
            vt[(((long)bb * 12 + hq) * 64 + (c - 128)) * 1024 + ss] = (bf16_t)v;
          }
        } else if (EPI == 1) {
          v = 0.5f * v * (1.0f + erff(v * 0.70710678118654752f));
          obf[idx] = (bf16_t)v;
        } else {
          of32[(long)blockIdx.z * ((long)M * N) + idx] = v;
        }
      }
    }
  }
}

// ---------------------------------------------------------------------------
// Logits GEMM: out[2048,32000] f32 = A[2048,768] @ We[32000,768]^T, both bf16.
// 256-thread 128x128 structure, BK=64, swizzled LDS, XCD-chunked M-fastest
// grid, NT fp32 stores, 3 blocks/CU.
// ---------------------------------------------------------------------------
__global__ __launch_bounds__(256, 3) void gemm_logits(
    const bf16_t* __restrict__ A, const bf16_t* __restrict__ W,
    float* __restrict__ out)
{
  __shared__ bf16_t As[128 * 64];
  __shared__ bf16_t Bs[128 * 64];
  const int tid  = threadIdx.x;
  const int lane = tid & 63;
  const int w    = tid >> 6;
  const int wr   = w >> 1;
  const int wc   = w & 1;
  const int d    = blockIdx.x;            // 0..3999
  const int wk   = (d & 7) * 500 + (d >> 3);
  const long m0  = (long)(wk & 15) * 128; // M fastest within XCD chunk
  const long n0  = (long)(wk >> 4) * 128;
  const int K = 768, N = 32000;

  f32x4 acc[4][4] = {};
  const int l7  = lane & 7;
  const int l15 = lane & 15;
  const int hi  = lane >> 4;
  const int rA  = wr * 64 + l15;
  const int rB  = wc * 64 + l15;

  for (int kt = 0; kt < K; kt += 64) {
#pragma unroll
    for (int i = 0; i < 4; ++i) {
      const int cl  = tid + i * 256;
      const int row = cl >> 3;
      const int j   = (cl & 7) ^ (row & 7);
      gload16(A + (m0 + row) * K + kt + (j << 3), As + cl * 8);
    }
#pragma unroll
    for (int i = 0; i < 4; ++i) {
      const int cl  = tid + i * 256;
      const int row = cl >> 3;
      const int j   = (cl & 7) ^ (row & 7);
      gload16(W + (n0 + row) * K + kt + (j << 3), Bs + cl * 8);
    }
    __syncthreads();
#pragma unroll
    for (int kk = 0; kk < 64; kk += 32) {
      const int ck = ((((kk >> 3) + hi) ^ l7) << 3);
      bf16x8 af[4], bfr[4];
#pragma unroll
      for (int m = 0; m < 4; ++m) af[m]  = *(const bf16x8*)(As + (rA + m * 16) * 64 + ck);
#pragma unroll
      for (int n = 0; n < 4; ++n) bfr[n] = *(const bf16x8*)(Bs + (rB + n * 16) * 64 + ck);
#pragma unroll
      for (int m = 0; m < 4; ++m)
#pragma unroll
        for (int n = 0; n < 4; ++n)
          acc[m][n] = __builtin_amdgcn_mfma_f32_16x16x32_bf16(af[m], bfr[n], acc[m][n], 0, 0, 0);
    }
    __syncthreads();
  }

  const int lr = hi << 2;
#pragma unroll
  for (int n = 0; n < 4; ++n) {
    const long gcol = n0 + wc * 64 + n * 16 + l15;
#pragma unroll
    for (int m = 0; m < 4; ++m) {
      const long grow0 = m0 + wr * 64 + m * 16 + lr;
#pragma unroll
      for (int r = 0; r < 4; ++r)
        __builtin_nontemporal_store(acc[m][n][r], &out[(grow0 + r) * N + gcol]);
    }
  }
}

// ---------------------------------------------------------------------------
// Flash attention: one wave per (b, h, 16 q-rows). KV blocks of 64, causal.
// CAUSAL LOAD-BALANCED block mapping: block = (bh, k), its 4 waves take
// qt in {2k, 2k+1, 63-2k, 62-2k} -- per-block work is constant (sum 126).
// Q,K from qkv [B][S][2304]; V from vT [bh][64][1024]. T13 defer-max.
// ---------------------------------------------------------------------------
__global__ __launch_bounds__(256) void attn_kernel(
    const bf16_t* __restrict__ qkv, const bf16_t* __restrict__ vT,
    bf16_t* __restrict__ aout)
{
  __shared__ bf16_t Plds[4][16 * 64];
  const int tid  = threadIdx.x;
  const int lane = tid & 63;
  const int w    = tid >> 6;
  const int bh   = blockIdx.x >> 4;      // 0..23
  const int k    = blockIdx.x & 15;      // 0..15
  const int qt   = (w < 2) ? (2 * k + w) : (63 - 2 * k - (w & 1));
  const int b    = bh / 12;
  const int h    = bh % 12;
  const int q0   = qt << 4;

  const bf16_t* base = qkv + (long)b * 1024 * 2304 + h * 192;
  const bf16_t* vtb  = vT + (long)bh * 64 * 1024;
  const int koff  = (lane >> 4) << 3;
  const int l15   = lane & 15;
  const int rbase = (lane >> 4) << 2;

  const bf16x8 qf0 = *(const bf16x8*)(base + (long)(q0 + l15) * 2304 + koff);
  const bf16x8 qf1 = *(const bf16x8*)(base + (long)(q0 + l15) * 2304 + 32 + koff);

  f32x4 acc[4] = {};
  float mrun[4], lrun[4];
#pragma unroll
  for (int r = 0; r < 4; ++r) { mrun[r] = -1e30f; lrun[r] = 0.f; }

  bf16_t* pl = &Plds[w][0];
  const int kbmax = (q0 + 15) >> 6;
  for (int kb = 0; kb <= kbmax; ++kb) {
    const int kv0 = kb << 6;
    const f32x4 z = {0.f, 0.f, 0.f, 0.f};
    f32x4 s[4];
    __builtin_amdgcn_s_setprio(1);
#pragma unroll
    for (int g = 0; g < 4; ++g) {
      const bf16_t* kr = base + 64 + (long)(kv0 + g * 16 + l15) * 2304;
      const bf16x8 ka = *(const bf16x8*)(kr + koff);
      const bf16x8 kb2 = *(const bf16x8*)(kr + 32 + koff);
      s[g] = __builtin_amdgcn_mfma_f32_16x16x32_bf16(qf0, ka, z, 0, 0, 0);
      s[g] = __builtin_amdgcn_mfma_f32_16x16x32_bf16(qf1, kb2, s[g], 0, 0, 0);
    }
    __builtin_amdgcn_s_setprio(0);

#pragma unroll
    for (int r = 0; r < 4; ++r) {
      const int qi = q0 + rbase + r;
      float v[4];
#pragma unroll
      for (int g = 0; g < 4; ++g)
        v[g] = (kv0 + g * 16 + l15 <= qi) ? s[g][r] * 0.125f : -1e9f;
      float mx = fmaxf(fmaxf(v[0], v[1]), fmaxf(v[2], v[3]));
#pragma unroll
      for (int dd = 1; dd < 16; dd <<= 1) mx = fmaxf(mx, __shfl_xor(mx, dd));
      if (mx > mrun[r] + 8.f) {
        const float sc = __expf(mrun[r] - mx);
        lrun[r] *= sc;
        acc[0][r] *= sc; acc[1][r] *= sc; acc[2][r] *= sc; acc[3][r] *= sc;
        mrun[r] = mx;
      }
      float p[4], sm = 0.f;
#pragma unroll
      for (int g = 0; g < 4; ++g) { p[g] = __expf(v[g] - mrun[r]); sm += p[g]; }
#pragma unroll
      for (int dd = 1; dd < 16; dd <<= 1) sm += __shfl_xor(sm, dd);
      lrun[r] += sm;
#pragma unroll
      for (int g = 0; g < 4; ++g)
        pl[(rbase + r) * 64 + g * 16 + l15] = (bf16_t)p[g];
    }
    asm volatile("s_waitcnt lgkmcnt(0)" ::: "memory");
    const bf16x8 pf0 = *(const bf16x8*)(pl + l15 * 64 + koff);
    const bf16x8 pf1 = *(const bf16x8*)(pl + l15 * 64 + 32 + koff);
    __builtin_amdgcn_s_setprio(1);
#pragma unroll
    for (int hh = 0; hh < 2; ++hh) {
      const bf16x8 pf = hh ? pf1 : pf0;
      const int sbase = kv0 + hh * 32 + koff;
#pragma unroll
      for (int cb = 0; cb < 4; ++cb) {
        const bf16x8 vf = *(const bf16x8*)(vtb + (long)(cb * 16 + l15) * 1024 + sbase);
        acc[cb] = __builtin_amdgcn_mfma_f32_16x16x32_bf16(pf, vf, acc[cb], 0, 0, 0);
      }
    }
    __builtin_amdgcn_s_setprio(0);
  }

#pragma unroll
  for (int cb = 0; cb < 4; ++cb)
#pragma unroll
    for (int r = 0; r < 4; ++r) {
      const float o = acc[cb][r] / lrun[r];
      aout[(long)(b * 1024 + q0 + rbase + r) * 768 + h * 64 + cb * 16 + l15] = (bf16_t)o;
    }
}

// ---------------------------------------------------------------------------
// Residual-folding LayerNorm: x += d[0] + d[1] (split-K partials from EPI6),
// write x back, then out = LN(x).
// ---------------------------------------------------------------------------
__global__ __launch_bounds__(256) void ln_fuse2(
    float* __restrict__ x, const float* __restrict__ dl,
    const float* __restrict__ g, const float* __restrict__ bta,
    bf16_t* __restrict__ out)
{
  const int row = blockIdx.x;
  const int tid = threadIdx.x;
  float* xr = x + (long)row * 768;
  const float* d0 = dl + (long)row * 768;
  const float* d1 = d0 + 1572864;
  float v[3];
#pragma unroll
  for (int k = 0; k < 3; ++k) {
    const int c = tid + k * 256;
    const float t = xr[c] + d0[c] + d1[c];
    v[k] = t;
    xr[c] = t;
  }
  float s  = v[0] + v[1] + v[2];
  float ss = v[0] * v[0] + v[1] * v[1] + v[2] * v[2];
#pragma unroll
  for (int d = 1; d < 64; d <<= 1) { s += __shfl_xor(s, d); ss += __shfl_xor(ss, d); }
  __shared__ float sh[8];
  const int lane = tid & 63, wv = tid >> 6;
  if (lane == 0) { sh[wv] = s; sh[4 + wv] = ss; }
  __syncthreads();
  s  = sh[0] + sh[1] + sh[2] + sh[3];
  ss = sh[4] + sh[5] + sh[6] + sh[7];
  const float mean = s * (1.0f / 768.0f);
  const float var  = ss * (1.0f / 768.0f) - mean * mean;
  const float inv  = rsqrtf(var + 1e-5f);
  bf16_t* orow = out + (long)row * 768;
#pragma unroll
  for (int k = 0; k < 3; ++k) {
    const int c = tid + k * 256;
    orow[c] = (bf16_t)(g[c] * ((v[k] - mean) * inv) + bta[c]);
  }
}

// ---------------------------------------------------------------------------
// Fused embedding + first LayerNorm:
// x = W_emb[id]*sqrt(768) + pos ; h = LN(x, g, b)
// ---------------------------------------------------------------------------
__global__ __launch_bounds__(256) void embed_ln(
    const int* __restrict__ ids, const float* __restrict__ We,
    const float* __restrict__ pos, const float* __restrict__ g,
    const float* __restrict__ bta, float* __restrict__ x,
    bf16_t* __restrict__ out)
{
  const int row = blockIdx.x;
  const int tid = threadIdx.x;
  const int sidx = row & 1023;
  const long id = ids[row];
  const float* wr = We + id * 768;
  const float* pr = pos + (long)sidx * 768;
  float* xr = x + (long)row * 768;
  float v[3];
#pragma unroll
  for (int k = 0; k < 3; ++k) {
    const int c = tid + k * 256;
    const float t = wr[c] * 27.712812921102035f + pr[c];
    v[k] = t;
    xr[c] = t;
  }
  float s  = v[0] + v[1] + v[2];
  float ss = v[0] * v[0] + v[1] * v[1] + v[2] * v[2];
#pragma unroll
  for (int d = 1; d < 64; d <<= 1) { s += __shfl_xor(s, d); ss += __shfl_xor(ss, d); }
  __shared__ float sh[8];
  const int lane = tid & 63, wv = tid >> 6;
  if (lane == 0) { sh[wv] = s; sh[4 + wv] = ss; }
  __syncthreads();
  s  = sh[0] + sh[1] + sh[2] + sh[3];
  ss = sh[4] + sh[5] + sh[6] + sh[7];
  const float mean = s * (1.0f / 768.0f);
  const float var  = ss * (1.0f / 768.0f) - mean * mean;
  const float inv  = rsqrtf(var + 1e-5f);
  bf16_t* orow = out + (long)row * 768;
#pragma unroll
  for (int k = 0; k < 3; ++k) {
    const int c = tid + k * 256;
    orow[c] = (bf16_t)(g[c] * ((v[k] - mean) * inv) + bta[c]);
  }
}

// ---------------------------------------------------------------------------
// Fused fp32 -> bf16 conversion of all 5 weight tensors (contiguous outputs).
// NT loads: the 302 MB fp32 weight stream is read exactly once -- keep it
// from sweeping L2/L3 ahead of embed_ln/QKV.
// ---------------------------------------------------------------------------
__global__ __launch_bounds__(256) void cvt_all_kernel(
    const float* __restrict__ s0, const float* __restrict__ s1,
    const float* __restrict__ s2, const float* __restrict__ s3,
    const float* __restrict__ s4, bf16_t* __restrict__ out)
{
  const int b = blockIdx.x;
  const float* src; long rel, obase;
  if      (b < 3456)  { src = s0; rel = (long)b * 2048;          obase = 0;        }
  else if (b < 4608)  { src = s1; rel = (long)(b - 3456) * 2048; obase = 7077888;  }
  else if (b < 9216)  { src = s2; rel = (long)(b - 4608) * 2048; obase = 9437184;  }
  else if (b < 13824) { src = s3; rel = (long)(b - 9216) * 2048; obase = 18874368; }
  else                { src = s4; rel = (long)(b - 13824) * 2048; obase = 28311552; }
  const long i = rel + (long)threadIdx.x * 8;
  const f32x4 a = __builtin_nontemporal_load((const f32x4*)(src + i));
  const f32x4 c = __builtin_nontemporal_load((const f32x4*)(src + i + 4));
  bf16x8 o;
#pragma unroll
  for (int j = 0; j < 4; ++j) { o[j] = (bf16_t)a[j]; o[4 + j] = (bf16_t)c[j]; }
  *(bf16x8*)(out + obase + i) = o;
}

// ---------------------------------------------------------------------------
extern "C" void kernel_launch(void* const* d_in, const int* in_sizes, int n_in,
                              void* d_out, int out_size, void* d_ws, size_t ws_size,
                              hipStream_t stream)
{
  const float* W_emb = (const float*)d_in[0];
  const float* pos   = (const float*)d_in[1];
  const float* n1g   = (const float*)d_in[2];
  const float* n1b   = (const float*)d_in[3];
  const float* qkvw  = (const float*)d_in[4];
  const float* qkvb  = (const float*)d_in[5];
  const float* projw = (const float*)d_in[6];
  const float* projb = (const float*)d_in[7];
  const float* n2g   = (const float*)d_in[8];
  const float* n2b   = (const float*)d_in[9];
  const float* f1w   = (const float*)d_in[10];
  const float* f1b   = (const float*)d_in[11];
  const float* f2w   = (const float*)d_in[12];
  const float* f2b   = (const float*)d_in[13];
  const float* fing  = (const float*)d_in[14];
  const float* finb  = (const float*)d_in[15];
  const int*   ids   = (const int*)d_in[16];
  float* out = (float*)d_out;

  char* ws = (char*)d_ws;
  float*  x     = (float*)(ws);                 // 2048*768 f32   = 6291456 B
  bf16_t* h     = (bf16_t*)(ws + 6291456);      // 2048*768 bf16  = 3145728 B
  bf16_t* qkv   = (bf16_t*)(ws + 9437184);      // 2048*2304 bf16 = 9437184 B
  bf16_t* attn  = (bf16_t*)(ws + 18874368);     // 2048*768 bf16
  bf16_t* ffn1o = (bf16_t*)(ws + 22020096);     // 2048*3072 bf16 = 12582912 B
  bf16_t* Wq    = (bf16_t*)(ws + 34603008);     // 4*2304*768   } contiguous
  bf16_t* Wp    = (bf16_t*)(ws + 48758784);     // 4*768*768    }
  bf16_t* W1    = (bf16_t*)(ws + 53477376);     // 4*3072*768   }
  bf16_t* W2    = (bf16_t*)(ws + 72351744);     // 4*768*3072   }
  bf16_t* We    = (bf16_t*)(ws + 91226112);     // 32000*768    }
  bf16_t* vT    = (bf16_t*)(ws + 140378112);    // 24*64*1024 bf16 = 3145728 B
  float*  dpart = (float*)(ws + 143523840);     // 2 x 2048*768 f32 = 12582912 B

  cvt_all_kernel<<<dim3(25824), 256, 0, stream>>>(qkvw, projw, f1w, f2w, W_emb, Wq);

  embed_ln<<<2048, 256, 0, stream>>>(ids, W_emb, pos, n1g, n1b, x, h);

  for (int i = 0; i < 4; ++i) {
    if (i > 0)
      ln_fuse2<<<2048, 256, 0, stream>>>(x, dpart, n1g + i * 768, n1b + i * 768, h);
    gemm_bt<5><<<dim3(36, 16), 128, 0, stream>>>(
        h, Wq + (long)i * 2304 * 768, qkvb + i * 2304, qkv, nullptr, vT,
        2048, 2304, 768, 768);
    attn_kernel<<<384, 256, 0, stream>>>(qkv, vT, attn);
    gemm_bt<6><<<dim3(12, 16, 2), 128, 0, stream>>>(
        attn, Wp + (long)i * 768 * 768, projb + i * 768, nullptr, dpart, nullptr,
        2048, 768, 768, 384);
    ln_fuse2<<<2048, 256, 0, stream>>>(x, dpart, n2g + i * 768, n2b + i * 768, h);
    gemm_bt<1><<<dim3(48, 16), 128, 0, stream>>>(
        h, W1 + (long)i * 3072 * 768, f1b + i * 3072, ffn1o, nullptr, nullptr,
        2048, 3072, 768, 768);
    gemm_bt<6><<<dim3(12, 16, 2), 128, 0, stream>>>(
        ffn1o, W2 + (long)i * 768 * 3072, f2b + i * 768, nullptr, dpart, nullptr,
        2048, 768, 3072, 1536);
  }
  ln_fuse2<<<2048, 256, 0, stream>>>(x, dpart, fing, finb, h);
  gemm_logits<<<dim3(4000), 256, 0, stream>>>(h, We, out);
}

// Round 17
// 756.440 us; speedup vs baseline: 1.0430x; 1.0013x over previous
//
#include <hip/hip_runtime.h>
#include <hip/hip_bf16.h>
#include <math.h>

typedef __bf16 bf16_t;
typedef __bf16 bf16x8 __attribute__((ext_vector_type(8)));
typedef float f32x4 __attribute__((ext_vector_type(4)));

// async 16B global->LDS (LDS dest must be wave-uniform base + lane*16)
__device__ __forceinline__ void gload16(const bf16_t* g, bf16_t* l) {
  __builtin_amdgcn_global_load_lds(
      (const __attribute__((address_space(1))) unsigned int*)g,
      (__attribute__((address_space(3))) unsigned int*)l, 16, 0, 0);
}

// LDS tiles are [rows][64] bf16 (128 B row stride), contents XOR-swizzled:
// LDS[row][chunk j] holds G[row][chunk j ^ (row&7)]  (chunk = 8 bf16 = 16 B).

// ---------------------------------------------------------------------------
// Layer GEMM: out[M,N] = A[M,K] @ W[N,K]^T (+bias, +epilogue)
// EPI 0: bf16 out = acc + bias            (generic)
// EPI 5: EPI0 + side-write V third into vT[bh][d][s]   (QKV, fused vtrans)
// EPI 1: bf16 out = gelu(acc + bias)      (FFN1)
// EPI 6: f32 partial d[z][idx] = acc (+bias at z=0)    (proj/FFN2 split-K)
// Tile 128(M)x64(N), BK=64, 128 threads = 2 waves, single-buffer LDS.
// XCD-CHUNKED GRID (bijective, nwg%8==0 for all uses): linear block id ->
// each XCD owns a contiguous N-range, M-fastest within it. A-tile (3 MB)
// becomes L2-resident per XCD; W panels stream once per XCD then L2-hit.
// Shrinks the 2-phase stage-drain bubble (L2 ~200cy vs L3/HBM 400-900, m126).
// ---------------------------------------------------------------------------
template<int EPI>
__global__ __launch_bounds__(128, 3) void gemm_bt(
    const bf16_t* __restrict__ A, const bf16_t* __restrict__ W,
    const float* __restrict__ bias,
    bf16_t* __restrict__ obf, float* __restrict__ of32, bf16_t* __restrict__ vt,
    int M, int N, int K, int kLen, int nwg8)   // nwg8 = (gridX*gridY)/8
{
  __shared__ bf16_t As[128 * 64];
  __shared__ bf16_t Bs[64 * 64];
  const int tid  = threadIdx.x;
  const int lane = tid & 63;
  const int w    = tid >> 6;          // 0..1, wave's 64-row band
  const int lin  = blockIdx.y * gridDim.x + blockIdx.x;
  const int wk   = (lin & 7) * nwg8 + (lin >> 3);   // bijective XCD chunk
  const long m0 = (long)(wk & 15) * 128;            // M fastest (16 M-blocks)
  const long n0 = (long)(wk >> 4) * 64;
  const int k0 = blockIdx.z * kLen;
  const int k1 = k0 + kLen;

  f32x4 acc[4][4] = {};

  const int l7  = lane & 7;
  const int l15 = lane & 15;
  const int hi  = lane >> 4;          // 0..3
  const int rA  = w * 64 + l15;

  for (int kt = k0; kt < k1; kt += 64) {
#pragma unroll
    for (int i = 0; i < 8; ++i) {
      const int cl  = tid + i * 128;
      const int row = cl >> 3;
      const int j   = (cl & 7) ^ (row & 7);
      gload16(A + (m0 + row) * K + kt + (j << 3), As + cl * 8);
    }
#pragma unroll
    for (int i = 0; i < 4; ++i) {
      const int cl  = tid + i * 128;
      const int row = cl >> 3;
      const int j   = (cl & 7) ^ (row & 7);
      gload16(W + (n0 + row) * K + kt + (j << 3), Bs + cl * 8);
    }
    __syncthreads();
#pragma unroll
    for (int kk = 0; kk < 64; kk += 32) {
      const int ck = ((((kk >> 3) + hi) ^ l7) << 3);   // swizzled chunk offset
      bf16x8 af[4], bfr[4];
#pragma unroll
      for (int m = 0; m < 4; ++m) af[m]  = *(const bf16x8*)(As + (rA + m * 16) * 64 + ck);
#pragma unroll
      for (int n = 0; n < 4; ++n) bfr[n] = *(const bf16x8*)(Bs + (l15 + n * 16) * 64 + ck);
#pragma unroll
      for (int m = 0; m < 4; ++m)
#pragma unroll
        for (int n = 0; n < 4; ++n)
          acc[m][n] = __builtin_amdgcn_mfma_f32_16x16x32_bf16(af[m], bfr[n], acc[m][n], 0, 0, 0);
    }
    __syncthreads();
  }

  // C/D layout: col = lane&15, row = (lane>>4)*4 + reg
  const int lr = hi << 2;
#pragma unroll
  for (int n = 0; n < 4; ++n) {
    const long gcol = n0 + n * 16 + l15;
    float bv = 0.f;
    if (EPI == 0 || EPI == 1 || EPI == 5) bv = bias[gcol];
    if (EPI == 6 && k0 == 0)  bv = bias[gcol];
    const int hq = (int)gcol / 192;          // head (EPI5)
    const int c  = (int)gcol - hq * 192;     // col within head
#pragma unroll
    for (int m = 0; m < 4; ++m) {
      const long grow0 = m0 + w * 64 + m * 16 + lr;
#pragma unroll
      for (int r = 0; r < 4; ++r) {
        float v = acc[m][n][r] + bv;
        const long idx = (grow0 + r) * N + gcol;
        if (EPI == 0 || EPI == 5) {
          obf[idx] = (bf16_t)v;
          if (EPI == 5 && c >= 128) {
            const int row = (int)(grow0 + r);
            const int bb = row >> 10, ss = row & 1023;
            vt[(((long)bb * 12 + hq) * 64 + (c - 128)) * 1024 + ss] = (bf16_t)v;
          }
        } else if (EPI == 1) {
          v = 0.5f * v * (1.0f + erff(v * 0.70710678118654752f));
          obf[idx] = (bf16_t)v;
        } else {
          of32[(long)blockIdx.z * ((long)M * N) + idx] = v;
        }
      }
    }
  }
}

// ---------------------------------------------------------------------------
// Logits GEMM: out[2048,32000] f32 = A[2048,768] @ We[32000,768]^T, both bf16.
// 256-thread 128x128 structure, BK=64, swizzled LDS, XCD-chunked M-fastest
// grid, NT fp32 stores, 3 blocks/CU.
// ---------------------------------------------------------------------------
__global__ __launch_bounds__(256, 3) void gemm_logits(
    const bf16_t* __restrict__ A, const bf16_t* __restrict__ W,
    float* __restrict__ out)
{
  __shared__ bf16_t As[128 * 64];
  __shared__ bf16_t Bs[128 * 64];
  const int tid  = threadIdx.x;
  const int lane = tid & 63;
  const int w    = tid >> 6;
  const int wr   = w >> 1;
  const int wc   = w & 1;
  const int d    = blockIdx.x;            // 0..3999
  const int wk   = (d & 7) * 500 + (d >> 3);
  const long m0  = (long)(wk & 15) * 128; // M fastest within XCD chunk
  const long n0  = (long)(wk >> 4) * 128;
  const int K = 768, N = 32000;

  f32x4 acc[4][4] = {};
  const int l7  = lane & 7;
  const int l15 = lane & 15;
  const int hi  = lane >> 4;
  const int rA  = wr * 64 + l15;
  const int rB  = wc * 64 + l15;

  for (int kt = 0; kt < K; kt += 64) {
#pragma unroll
    for (int i = 0; i < 4; ++i) {
      const int cl  = tid + i * 256;
      const int row = cl >> 3;
      const int j   = (cl & 7) ^ (row & 7);
      gload16(A + (m0 + row) * K + kt + (j << 3), As + cl * 8);
    }
#pragma unroll
    for (int i = 0; i < 4; ++i) {
      const int cl  = tid + i * 256;
      const int row = cl >> 3;
      const int j   = (cl & 7) ^ (row & 7);
      gload16(W + (n0 + row) * K + kt + (j << 3), Bs + cl * 8);
    }
    __syncthreads();
#pragma unroll
    for (int kk = 0; kk < 64; kk += 32) {
      const int ck = ((((kk >> 3) + hi) ^ l7) << 3);
      bf16x8 af[4], bfr[4];
#pragma unroll
      for (int m = 0; m < 4; ++m) af[m]  = *(const bf16x8*)(As + (rA + m * 16) * 64 + ck);
#pragma unroll
      for (int n = 0; n < 4; ++n) bfr[n] = *(const bf16x8*)(Bs + (rB + n * 16) * 64 + ck);
#pragma unroll
      for (int m = 0; m < 4; ++m)
#pragma unroll
        for (int n = 0; n < 4; ++n)
          acc[m][n] = __builtin_amdgcn_mfma_f32_16x16x32_bf16(af[m], bfr[n], acc[m][n], 0, 0, 0);
    }
    __syncthreads();
  }

  const int lr = hi << 2;
#pragma unroll
  for (int n = 0; n < 4; ++n) {
    const long gcol = n0 + wc * 64 + n * 16 + l15;
#pragma unroll
    for (int m = 0; m < 4; ++m) {
      const long grow0 = m0 + wr * 64 + m * 16 + lr;
#pragma unroll
      for (int r = 0; r < 4; ++r)
        __builtin_nontemporal_store(acc[m][n][r], &out[(grow0 + r) * N + gcol]);
    }
  }
}

// ---------------------------------------------------------------------------
// Flash attention: one wave per (b, h, 16 q-rows). KV blocks of 64, causal.
// CAUSAL LOAD-BALANCED block mapping: block = (bh, k), its 4 waves take
// qt in {2k, 2k+1, 63-2k, 62-2k} -- per-block work is constant (sum 126).
// Q,K from qkv [B][S][2304]; V from vT [bh][64][1024]. T13 defer-max.
// ---------------------------------------------------------------------------
__global__ __launch_bounds__(256) void attn_kernel(
    const bf16_t* __restrict__ qkv, const bf16_t* __restrict__ vT,
    bf16_t* __restrict__ aout)
{
  __shared__ bf16_t Plds[4][16 * 64];
  const int tid  = threadIdx.x;
  const int lane = tid & 63;
  const int w    = tid >> 6;
  const int bh   = blockIdx.x >> 4;      // 0..23
  const int k    = blockIdx.x & 15;      // 0..15
  const int qt   = (w < 2) ? (2 * k + w) : (63 - 2 * k - (w & 1));
  const int b    = bh / 12;
  const int h    = bh % 12;
  const int q0   = qt << 4;

  const bf16_t* base = qkv + (long)b * 1024 * 2304 + h * 192;
  const bf16_t* vtb  = vT + (long)bh * 64 * 1024;
  const int koff  = (lane >> 4) << 3;
  const int l15   = lane & 15;
  const int rbase = (lane >> 4) << 2;

  const bf16x8 qf0 = *(const bf16x8*)(base + (long)(q0 + l15) * 2304 + koff);
  const bf16x8 qf1 = *(const bf16x8*)(base + (long)(q0 + l15) * 2304 + 32 + koff);

  f32x4 acc[4] = {};
  float mrun[4], lrun[4];
#pragma unroll
  for (int r = 0; r < 4; ++r) { mrun[r] = -1e30f; lrun[r] = 0.f; }

  bf16_t* pl = &Plds[w][0];
  const int kbmax = (q0 + 15) >> 6;
  for (int kb = 0; kb <= kbmax; ++kb) {
    const int kv0 = kb << 6;
    const f32x4 z = {0.f, 0.f, 0.f, 0.f};
    f32x4 s[4];
    __builtin_amdgcn_s_setprio(1);
#pragma unroll
    for (int g = 0; g < 4; ++g) {
      const bf16_t* kr = base + 64 + (long)(kv0 + g * 16 + l15) * 2304;
      const bf16x8 ka = *(const bf16x8*)(kr + koff);
      const bf16x8 kb2 = *(const bf16x8*)(kr + 32 + koff);
      s[g] = __builtin_amdgcn_mfma_f32_16x16x32_bf16(qf0, ka, z, 0, 0, 0);
      s[g] = __builtin_amdgcn_mfma_f32_16x16x32_bf16(qf1, kb2, s[g], 0, 0, 0);
    }
    __builtin_amdgcn_s_setprio(0);

#pragma unroll
    for (int r = 0; r < 4; ++r) {
      const int qi = q0 + rbase + r;
      float v[4];
#pragma unroll
      for (int g = 0; g < 4; ++g)
        v[g] = (kv0 + g * 16 + l15 <= qi) ? s[g][r] * 0.125f : -1e9f;
      float mx = fmaxf(fmaxf(v[0], v[1]), fmaxf(v[2], v[3]));
#pragma unroll
      for (int dd = 1; dd < 16; dd <<= 1) mx = fmaxf(mx, __shfl_xor(mx, dd));
      if (mx > mrun[r] + 8.f) {
        const float sc = __expf(mrun[r] - mx);
        lrun[r] *= sc;
        acc[0][r] *= sc; acc[1][r] *= sc; acc[2][r] *= sc; acc[3][r] *= sc;
        mrun[r] = mx;
      }
      float p[4], sm = 0.f;
#pragma unroll
      for (int g = 0; g < 4; ++g) { p[g] = __expf(v[g] - mrun[r]); sm += p[g]; }
#pragma unroll
      for (int dd = 1; dd < 16; dd <<= 1) sm += __shfl_xor(sm, dd);
      lrun[r] += sm;
#pragma unroll
      for (int g = 0; g < 4; ++g)
        pl[(rbase + r) * 64 + g * 16 + l15] = (bf16_t)p[g];
    }
    asm volatile("s_waitcnt lgkmcnt(0)" ::: "memory");
    const bf16x8 pf0 = *(const bf16x8*)(pl + l15 * 64 + koff);
    const bf16x8 pf1 = *(const bf16x8*)(pl + l15 * 64 + 32 + koff);
    __builtin_amdgcn_s_setprio(1);
#pragma unroll
    for (int hh = 0; hh < 2; ++hh) {
      const bf16x8 pf = hh ? pf1 : pf0;
      const int sbase = kv0 + hh * 32 + koff;
#pragma unroll
      for (int cb = 0; cb < 4; ++cb) {
        const bf16x8 vf = *(const bf16x8*)(vtb + (long)(cb * 16 + l15) * 1024 + sbase);
        acc[cb] = __builtin_amdgcn_mfma_f32_16x16x32_bf16(pf, vf, acc[cb], 0, 0, 0);
      }
    }
    __builtin_amdgcn_s_setprio(0);
  }

#pragma unroll
  for (int cb = 0; cb < 4; ++cb)
#pragma unroll
    for (int r = 0; r < 4; ++r) {
      const float o = acc[cb][r] / lrun[r];
      aout[(long)(b * 1024 + q0 + rbase + r) * 768 + h * 64 + cb * 16 + l15] = (bf16_t)o;
    }
}

// ---------------------------------------------------------------------------
// Residual-folding LayerNorm: x += d[0] + d[1] (split-K partials from EPI6),
// write x back, then out = LN(x).
// ---------------------------------------------------------------------------
__global__ __launch_bounds__(256) void ln_fuse2(
    float* __restrict__ x, const float* __restrict__ dl,
    const float* __restrict__ g, const float* __restrict__ bta,
    bf16_t* __restrict__ out)
{
  const int row = blockIdx.x;
  const int tid = threadIdx.x;
  float* xr = x + (long)row * 768;
  const float* d0 = dl + (long)row * 768;
  const float* d1 = d0 + 1572864;
  float v[3];
#pragma unroll
  for (int k = 0; k < 3; ++k) {
    const int c = tid + k * 256;
    const float t = xr[c] + d0[c] + d1[c];
    v[k] = t;
    xr[c] = t;
  }
  float s  = v[0] + v[1] + v[2];
  float ss = v[0] * v[0] + v[1] * v[1] + v[2] * v[2];
#pragma unroll
  for (int d = 1; d < 64; d <<= 1) { s += __shfl_xor(s, d); ss += __shfl_xor(ss, d); }
  __shared__ float sh[8];
  const int lane = tid & 63, wv = tid >> 6;
  if (lane == 0) { sh[wv] = s; sh[4 + wv] = ss; }
  __syncthreads();
  s  = sh[0] + sh[1] + sh[2] + sh[3];
  ss = sh[4] + sh[5] + sh[6] + sh[7];
  const float mean = s * (1.0f / 768.0f);
  const float var  = ss * (1.0f / 768.0f) - mean * mean;
  const float inv  = rsqrtf(var + 1e-5f);
  bf16_t* orow = out + (long)row * 768;
#pragma unroll
  for (int k = 0; k < 3; ++k) {
    const int c = tid + k * 256;
    orow[c] = (bf16_t)(g[c] * ((v[k] - mean) * inv) + bta[c]);
  }
}

// ---------------------------------------------------------------------------
// Fused embedding + first LayerNorm:
// x = W_emb[id]*sqrt(768) + pos ; h = LN(x, g, b)
// ---------------------------------------------------------------------------
__global__ __launch_bounds__(256) void embed_ln(
    const int* __restrict__ ids, const float* __restrict__ We,
    const float* __restrict__ pos, const float* __restrict__ g,
    const float* __restrict__ bta, float* __restrict__ x,
    bf16_t* __restrict__ out)
{
  const int row = blockIdx.x;
  const int tid = threadIdx.x;
  const int sidx = row & 1023;
  const long id = ids[row];
  const float* wr = We + id * 768;
  const float* pr = pos + (long)sidx * 768;
  float* xr = x + (long)row * 768;
  float v[3];
#pragma unroll
  for (int k = 0; k < 3; ++k) {
    const int c = tid + k * 256;
    const float t = wr[c] * 27.712812921102035f + pr[c];
    v[k] = t;
    xr[c] = t;
  }
  float s  = v[0] + v[1] + v[2];
  float ss = v[0] * v[0] + v[1] * v[1] + v[2] * v[2];
#pragma unroll
  for (int d = 1; d < 64; d <<= 1) { s += __shfl_xor(s, d); ss += __shfl_xor(ss, d); }
  __shared__ float sh[8];
  const int lane = tid & 63, wv = tid >> 6;
  if (lane == 0) { sh[wv] = s; sh[4 + wv] = ss; }
  __syncthreads();
  s  = sh[0] + sh[1] + sh[2] + sh[3];
  ss = sh[4] + sh[5] + sh[6] + sh[7];
  const float mean = s * (1.0f / 768.0f);
  const float var  = ss * (1.0f / 768.0f) - mean * mean;
  const float inv  = rsqrtf(var + 1e-5f);
  bf16_t* orow = out + (long)row * 768;
#pragma unroll
  for (int k = 0; k < 3; ++k) {
    const int c = tid + k * 256;
    orow[c] = (bf16_t)(g[c] * ((v[k] - mean) * inv) + bta[c]);
  }
}

// ---------------------------------------------------------------------------
// Fused fp32 -> bf16 conversion of all 5 weight tensors (contiguous outputs).
// NT loads: the one-shot fp32 weight stream must not sweep L2/L3.
// ---------------------------------------------------------------------------
__global__ __launch_bounds__(256) void cvt_all_kernel(
    const float* __restrict__ s0, const float* __restrict__ s1,
    const float* __restrict__ s2, const float* __restrict__ s3,
    const float* __restrict__ s4, bf16_t* __restrict__ out)
{
  const int b = blockIdx.x;
  const float* src; long rel, obase;
  if      (b < 3456)  { src = s0; rel = (long)b * 2048;          obase = 0;        }
  else if (b < 4608)  { src = s1; rel = (long)(b - 3456) * 2048; obase = 7077888;  }
  else if (b < 9216)  { src = s2; rel = (long)(b - 4608) * 2048; obase = 9437184;  }
  else if (b < 13824) { src = s3; rel = (long)(b - 9216) * 2048; obase = 18874368; }
  else                { src = s4; rel = (long)(b - 13824) * 2048; obase = 28311552; }
  const long i = rel + (long)threadIdx.x * 8;
  const f32x4 a = __builtin_nontemporal_load((const f32x4*)(src + i));
  const f32x4 c = __builtin_nontemporal_load((const f32x4*)(src + i + 4));
  bf16x8 o;
#pragma unroll
  for (int j = 0; j < 4; ++j) { o[j] = (bf16_t)a[j]; o[4 + j] = (bf16_t)c[j]; }
  *(bf16x8*)(out + obase + i) = o;
}

// ---------------------------------------------------------------------------
extern "C" void kernel_launch(void* const* d_in, const int* in_sizes, int n_in,
                              void* d_out, int out_size, void* d_ws, size_t ws_size,
                              hipStream_t stream)
{
  const float* W_emb = (const float*)d_in[0];
  const float* pos   = (const float*)d_in[1];
  const float* n1g   = (const float*)d_in[2];
  const float* n1b   = (const float*)d_in[3];
  const float* qkvw  = (const float*)d_in[4];
  const float* qkvb  = (const float*)d_in[5];
  const float* projw = (const float*)d_in[6];
  const float* projb = (const float*)d_in[7];
  const float* n2g   = (const float*)d_in[8];
  const float* n2b   = (const float*)d_in[9];
  const float* f1w   = (const float*)d_in[10];
  const float* f1b   = (const float*)d_in[11];
  const float* f2w   = (const float*)d_in[12];
  const float* f2b   = (const float*)d_in[13];
  const float* fing  = (const float*)d_in[14];
  const float* finb  = (const float*)d_in[15];
  const int*   ids   = (const int*)d_in[16];
  float* out = (float*)d_out;

  char* ws = (char*)d_ws;
  float*  x     = (float*)(ws);                 // 2048*768 f32   = 6291456 B
  bf16_t* h     = (bf16_t*)(ws + 6291456);      // 2048*768 bf16  = 3145728 B
  bf16_t* qkv   = (bf16_t*)(ws + 9437184);      // 2048*2304 bf16 = 9437184 B
  bf16_t* attn  = (bf16_t*)(ws + 18874368);     // 2048*768 bf16
  bf16_t* ffn1o = (bf16_t*)(ws + 22020096);     // 2048*3072 bf16 = 12582912 B
  bf16_t* Wq    = (bf16_t*)(ws + 34603008);     // 4*2304*768   } contiguous
  bf16_t* Wp    = (bf16_t*)(ws + 48758784);     // 4*768*768    }
  bf16_t* W1    = (bf16_t*)(ws + 53477376);     // 4*3072*768   }
  bf16_t* W2    = (bf16_t*)(ws + 72351744);     // 4*768*3072   }
  bf16_t* We    = (bf16_t*)(ws + 91226112);     // 32000*768    }
  bf16_t* vT    = (bf16_t*)(ws + 140378112);    // 24*64*1024 bf16 = 3145728 B
  float*  dpart = (float*)(ws + 143523840);     // 2 x 2048*768 f32 = 12582912 B

  cvt_all_kernel<<<dim3(25824), 256, 0, stream>>>(qkvw, projw, f1w, f2w, W_emb, Wq);

  embed_ln<<<2048, 256, 0, stream>>>(ids, W_emb, pos, n1g, n1b, x, h);

  for (int i = 0; i < 4; ++i) {
    if (i > 0)
      ln_fuse2<<<2048, 256, 0, stream>>>(x, dpart, n1g + i * 768, n1b + i * 768, h);
    gemm_bt<5><<<dim3(36, 16), 128, 0, stream>>>(
        h, Wq + (long)i * 2304 * 768, qkvb + i * 2304, qkv, nullptr, vT,
        2048, 2304, 768, 768, 72);
    attn_kernel<<<384, 256, 0, stream>>>(qkv, vT, attn);
    gemm_bt<6><<<dim3(12, 16, 2), 128, 0, stream>>>(
        attn, Wp + (long)i * 768 * 768, projb + i * 768, nullptr, dpart, nullptr,
        2048, 768, 768, 384, 24);
    ln_fuse2<<<2048, 256, 0, stream>>>(x, dpart, n2g + i * 768, n2b + i * 768, h);
    gemm_bt<1><<<dim3(48, 16), 128, 0, stream>>>(
        h, W1 + (long)i * 3072 * 768, f1b + i * 3072, ffn1o, nullptr, nullptr,
        2048, 3072, 768, 768, 96);
    gemm_bt<6><<<dim3(12, 16, 2), 128, 0, stream>>>(
        ffn1o, W2 + (long)i * 768 * 3072, f2b + i * 768, nullptr, dpart, nullptr,
        2048, 768, 3072, 1536, 24);
  }
  ln_fuse2<<<2048, 256, 0, stream>>>(x, dpart, fing, finb, h);
  gemm_logits<<<dim3(4000), 256, 0, stream>>>(h, We, out);
}